// Round 10
// baseline (150.776 us; speedup 1.0000x reference)
//
#include <hip/hip_runtime.h>
#include <hip/hip_bf16.h>

// Problem constants
#define CO    128
#define CI    128
#define NPIX  3136   // 56*56
#define PH    58
#define PPIX  3364   // 58*58
#define HPX4  348    // halo pixels per 4-row tile: 6 padded rows * 58
#define SROW2 144    // LDS bytes per halo pixel per ci-half: 128 data + 16 pad

typedef __bf16 bf16x8 __attribute__((ext_vector_type(8)));
typedef float  f32x4  __attribute__((ext_vector_type(4)));
typedef float  f32x16 __attribute__((ext_vector_type(16)));

// ---------------------------------------------------------------------------
// Fused prep: [0,2048) weights | [2048,2504) border zero | [2504,4072) transpose.
// it layout: [b][ci-half h][3364 px][64 ci]  (round 3-5 proven version).
// ---------------------------------------------------------------------------
__global__ void prep_all(const float* __restrict__ in,
                         const float* __restrict__ eps,
                         const float* __restrict__ psi,
                         const float* __restrict__ mu,
                         __bf16* __restrict__ wt,
                         __bf16* __restrict__ it) {
  __shared__ __align__(16) char smem[32256];
  const int bx = blockIdx.x, tid = threadIdx.x;

  if (bx < 2048) {
    // ---- weights phase: block covers idx0..idx0+255 (one b, two co) ----
    float* Ebuf = (float*)smem;              // 2304 f32
    float* Pbuf = (float*)(smem + 9216);     // 2304 f32
    float* Mbuf = (float*)(smem + 18432);    // 2304 f32
    __bf16* Wb  = (__bf16*)(smem + 27648);   // [9][256] bf16
    const int idx0  = bx * 256;              // multiple of 256 -> ci0 = 0
    const int b     = idx0 >> 14;            // 64 blocks per b, no straddle
    const int coci0 = idx0 & 16383;          // co0*CI
    const f32x4* esrc = (const f32x4*)(eps + (size_t)idx0 * 9);
    const f32x4* psrc = (const f32x4*)(psi + (size_t)coci0 * 9);
    const f32x4* msrc = (const f32x4*)(mu  + (size_t)coci0 * 9);
#pragma unroll
    for (int i = 0; i < 3; ++i) {            // 576 f32x4 per array
      int j = i * 256 + tid;
      if (j < 576) {
        ((f32x4*)Ebuf)[j] = esrc[j];
        ((f32x4*)Pbuf)[j] = psrc[j];
        ((f32x4*)Mbuf)[j] = msrc[j];
      }
    }
    __syncthreads();
#pragma unroll
    for (int p = 0; p < 9; ++p) {
      float v = Ebuf[tid * 9 + p] * __expf(Pbuf[tid * 9 + p]) + Mbuf[tid * 9 + p];
      Wb[p * 256 + tid] = (__bf16)v;
    }
    __syncthreads();
    __bf16* wb = wt + (size_t)b * 9 * CO * CI + coci0;
#pragma unroll
    for (int i = 0; i < 2; ++i) {
      int s = i * 256 + tid;
      if (s < 288) {
        int p = s >> 5, j = s & 31;
        *(f32x4*)(wb + (size_t)p * CO * CI + j * 8) =
            *(const f32x4*)&Wb[p * 256 + j * 8];
      }
    }
  } else if (bx < 2504) {
    int cid = (bx - 2048) * 256 + tid;
    int pid = cid >> 4;
    int chunk = cid & 15;                    // 16 chunks of 16B per pixel
    int h  = chunk >> 3;                     // ci-half
    int c8 = chunk & 7;
    int b = pid / 228;
    int e = pid - b * 228;
    int ph, pw;
    if (e < 58)       { ph = 0;       pw = e; }
    else if (e < 116) { ph = 57;      pw = e - 58; }
    else if (e < 172) { ph = e - 115; pw = 0; }
    else              { ph = e - 171; pw = 57; }
    f32x4 z = {0.f, 0.f, 0.f, 0.f};
    *(f32x4*)&it[((size_t)(b * 2 + h) * PPIX + ph * PH + pw) * 64 + c8 * 8] = z;
  } else {
    __bf16 (*T)[136] = (__bf16(*)[136])smem;   // [64][136]
    int tx = bx - 2504;
    int b  = tx / 49;
    int p0 = (tx - b * 49) * 64;
    const float* src = in + (size_t)b * CI * NPIX;
#pragma unroll
    for (int jj = 0; jj < 8; ++jj) {
      int c = jj * 256 + tid;
      int ci = c >> 4, xc = c & 15;
      float4 v = *(const float4*)(src + (size_t)ci * NPIX + p0 + xc * 4);
      T[xc * 4 + 0][ci] = (__bf16)v.x;
      T[xc * 4 + 1][ci] = (__bf16)v.y;
      T[xc * 4 + 2][ci] = (__bf16)v.z;
      T[xc * 4 + 3][ci] = (__bf16)v.w;
    }
    __syncthreads();
#pragma unroll
    for (int jj = 0; jj < 4; ++jj) {
      int c = jj * 256 + tid;
      int pl = c >> 4, xc = c & 15;
      int h  = xc >> 3;
      int c8 = xc & 7;
      int pix = p0 + pl;
      int oh = pix / 56, ow = pix - oh * 56;
      int ppix = (oh + 1) * PH + (ow + 1);
      *(f32x4*)&it[((size_t)(b * 2 + h) * PPIX + ppix) * 64 + c8 * 8] =
          *(const f32x4*)&T[pl][xc * 8];
    }
  }
}

// ---------------------------------------------------------------------------
// GEMM/conv with 32x32x16 MFMA — round-8 structure, setprio REMOVED:
//   block = 128 co x 224 n (4 image rows), 4 waves by co-group: wave =
//   32 co x 224 n = 7 n-frags of 32 pixels, acc = 7 x f32x16 (112 AGPR;
//   ~182 unified regs -> 2 waves/SIMD).  Per step (one tap x 16 ci):
//   1 A-load (16B/lane), 7 ds_read_b128, 7 v_mfma_f32_32x32x16_bf16.
//   72 steps = 2 ci-halves x 9 taps x 4 kk; restage at midpoint (2
//   barriers; otherwise barrier-free).  A: dist-2 register ring.
//   NO s_setprio: the per-step setprio(1)/(0) pairs acted as 144 scheduler
//   fences in the unrolled body, pinning each step's ds_reads/waits inside
//   its step and exposing ~1000cy of latency per step (R8/R9 both ran
//   ~1350cy/step vs a ~300cy static critical path).  Unfenced, the
//   compiler can software-pipeline ds_reads/A-waits across steps
//   (m97-verified fine-grained lgkmcnt/vmcnt scheduling).
//   Grid 14 tiles x 32 b = 448 blocks.
// ---------------------------------------------------------------------------
__global__ __launch_bounds__(256, 2) void bconv_gemm(
    const __bf16* __restrict__ wt,   // [b][9][128 co][128 ci]
    const __bf16* __restrict__ it,   // [b][2 h][3364 px][64 ci]
    float* __restrict__ out) {       // [b][128 co][3136 n]
  __shared__ __align__(16) char Bsh[HPX4 * SROW2];   // 50112 B
  const int tid  = threadIdx.x;
  const int w    = tid >> 6;
  const int lane = tid & 63;
  const int l31  = lane & 31;
  const int hi8  = lane >> 5;

  // Decode: lin = x + 8*(tile*4 + bhi); b = x + 8*bhi -> same-b blocks share an XCD
  const int lin = blockIdx.x;
  const int x   = lin & 7;
  const int j   = lin >> 3;          // 0..55
  const int bhi = j & 3;
  const int tile = j >> 2;           // 0..13
  const int b   = x + 8 * bhi;
  const int oh0 = tile * 4;          // first output row of this tile

  // ---- halo staging, ci-half 0: 348 px x 8 chunks of 16B = 2784 chunks ----
  const __bf16* hsrc0 = it + ((size_t)(b * 2 + 0) * PPIX + oh0 * PH) * 64;
  const __bf16* hsrc1 = it + ((size_t)(b * 2 + 1) * PPIX + oh0 * PH) * 64;
#pragma unroll
  for (int i = 0; i < 11; ++i) {
    int idx = i * 256 + tid;
    if (idx < HPX4 * 8) {
      int px = idx >> 3, sub = idx & 7;
      *(f32x4*)&Bsh[px * SROW2 + sub * 16] = *(const f32x4*)(hsrc0 + (size_t)idx * 8);
    }
  }
  __syncthreads();

  // ---- per-lane B fragment LDS byte-bases (tap (0,0), kk=0) ----
  // frag nf: pixel n = nf*32 + l31 (flat in the 4x56 tile); k = hi8*8 + e
  int bbase[7];
#pragma unroll
  for (int nf = 0; nf < 7; ++nf) {
    int n = nf * 32 + l31;                   // 0..223
    int orow = n / 56;
    int ocol = n - orow * 56;
    bbase[nf] = (orow * PH + ocol) * SROW2 + hi8 * 16;
  }

  // ---- per-lane A global base (elements): co = co0 + l31, k = hi8*8 + e ----
  const int co0 = w * 32;
  const __bf16* wtb = wt + (size_t)b * 9 * CO * CI;
  const int ab = (co0 + l31) * CI + hi8 * 8;

  f32x16 acc[7] = {};
  // distance-2 A-prefetch ring (statically indexed under full unroll)
  // step t: h = t/36, r = t%36, p = r>>2 (tap), kk = r&3 (16-ci chunk)
  // A element offset = p*CO*CI + h*64 + kk*16
  bf16x8 areg[3];
  areg[0] = *(const bf16x8*)(wtb + ab);          // t=0: p0 kk0 h0
  areg[1] = *(const bf16x8*)(wtb + 16 + ab);     // t=1: p0 kk1 h0

#pragma unroll
  for (int s = 0; s < 72; ++s) {
    if (s == 36) {
      __syncthreads();                       // all waves done reading half 0
#pragma unroll
      for (int i = 0; i < 11; ++i) {
        int idx = i * 256 + tid;
        if (idx < HPX4 * 8) {
          int px = idx >> 3, sub = idx & 7;
          *(f32x4*)&Bsh[px * SROW2 + sub * 16] = *(const f32x4*)(hsrc1 + (size_t)idx * 8);
        }
      }
      __syncthreads();
    }
    // prefetch A for step s+2
    if (s < 70) {
      const int tn  = s + 2;
      const int hn  = tn / 36;
      const int rn  = tn % 36;
      const int pn  = rn >> 2;
      const int kkn = rn & 3;
      areg[tn % 3] = *(const bf16x8*)(wtb + pn * (CO * CI) + hn * 64 + kkn * 16 + ab);
    }
    const int r  = s % 36;
    const int p  = r >> 2;
    const int kk = r & 3;
    const int kh = p / 3, kw = p - kh * 3;
    const int tapb = (kh * PH + kw) * SROW2 + kk * 32;   // compile-time (unrolled)
#pragma unroll
    for (int nf = 0; nf < 7; ++nf) {
      bf16x8 bfr = *(const bf16x8*)&Bsh[bbase[nf] + tapb];
      acc[nf] = __builtin_amdgcn_mfma_f32_32x32x16_bf16(areg[s % 3], bfr, acc[nf], 0, 0, 0);
    }
  }

  // ---- epilogue: col(l31)=n, row = (reg&3)+8*(reg>>2)+4*hi8 = co offset ----
  float* ob = out + (size_t)b * CO * NPIX + oh0 * 56;
#pragma unroll
  for (int nf = 0; nf < 7; ++nf) {
#pragma unroll
    for (int rg = 0; rg < 16; ++rg) {
      int co = co0 + (rg & 3) + 8 * (rg >> 2) + 4 * hi8;
      ob[(size_t)co * NPIX + nf * 32 + l31] = acc[nf][rg];
    }
  }
}

// ---------------------------------------------------------------------------
extern "C" void kernel_launch(void* const* d_in, const int* in_sizes, int n_in,
                              void* d_out, int out_size, void* d_ws, size_t ws_size,
                              hipStream_t stream) {
  const float* inp = (const float*)d_in[0];   // [32,128,56,56]
  const float* eps = (const float*)d_in[1];   // [32,128,128,3,3]
  const float* psi = (const float*)d_in[2];   // [128,128,3,3]
  const float* mu  = (const float*)d_in[3];   // [128,128,3,3]

  // ws layout: wt (9,437,184 B) | it (27,557,888 B)
  __bf16* wt = (__bf16*)d_ws;
  __bf16* it = (__bf16*)((char*)d_ws + 9437184);

  prep_all<<<4072, 256, 0, stream>>>(inp, eps, psi, mu, wt, it);
  bconv_gemm<<<448, 256, 0, stream>>>(wt, it, (float*)d_out);
}

// Round 11
// 146.576 us; speedup vs baseline: 1.0287x; 1.0287x over previous
//
#include <hip/hip_runtime.h>
#include <hip/hip_bf16.h>

// Problem constants
#define CO    128
#define CI    128
#define NPIX  3136   // 56*56
#define PH    58
#define PPIX  3364   // 58*58
#define HPX4  348    // halo pixels per 4-row tile: 6 padded rows * 58
#define SROW2 144    // LDS bytes per halo pixel per ci-half: 128 data + 16 pad

typedef __bf16 bf16x8 __attribute__((ext_vector_type(8)));
typedef float  f32x4  __attribute__((ext_vector_type(4)));
typedef float  f32x16 __attribute__((ext_vector_type(16)));

// ---------------------------------------------------------------------------
// Fused prep: [0,2048) weights | [2048,2504) border zero | [2504,4072) transpose.
// it layout: [b][ci-half h][3364 px][64 ci].
// ---------------------------------------------------------------------------
__global__ void prep_all(const float* __restrict__ in,
                         const float* __restrict__ eps,
                         const float* __restrict__ psi,
                         const float* __restrict__ mu,
                         __bf16* __restrict__ wt,
                         __bf16* __restrict__ it) {
  __shared__ __align__(16) char smem[32256];
  const int bx = blockIdx.x, tid = threadIdx.x;

  if (bx < 2048) {
    // ---- weights phase: block covers idx0..idx0+255 (one b, two co) ----
    float* Ebuf = (float*)smem;              // 2304 f32
    float* Pbuf = (float*)(smem + 9216);     // 2304 f32
    float* Mbuf = (float*)(smem + 18432);    // 2304 f32
    __bf16* Wb  = (__bf16*)(smem + 27648);   // [9][256] bf16
    const int idx0  = bx * 256;              // multiple of 256 -> ci0 = 0
    const int b     = idx0 >> 14;            // 64 blocks per b, no straddle
    const int coci0 = idx0 & 16383;          // co0*CI
    const f32x4* esrc = (const f32x4*)(eps + (size_t)idx0 * 9);
    const f32x4* psrc = (const f32x4*)(psi + (size_t)coci0 * 9);
    const f32x4* msrc = (const f32x4*)(mu  + (size_t)coci0 * 9);
#pragma unroll
    for (int i = 0; i < 3; ++i) {            // 576 f32x4 per array
      int j = i * 256 + tid;
      if (j < 576) {
        ((f32x4*)Ebuf)[j] = esrc[j];
        ((f32x4*)Pbuf)[j] = psrc[j];
        ((f32x4*)Mbuf)[j] = msrc[j];
      }
    }
    __syncthreads();
#pragma unroll
    for (int p = 0; p < 9; ++p) {
      float v = Ebuf[tid * 9 + p] * __expf(Pbuf[tid * 9 + p]) + Mbuf[tid * 9 + p];
      Wb[p * 256 + tid] = (__bf16)v;
    }
    __syncthreads();
    __bf16* wb = wt + (size_t)b * 9 * CO * CI + coci0;
#pragma unroll
    for (int i = 0; i < 2; ++i) {
      int s = i * 256 + tid;
      if (s < 288) {
        int p = s >> 5, j = s & 31;
        *(f32x4*)(wb + (size_t)p * CO * CI + j * 8) =
            *(const f32x4*)&Wb[p * 256 + j * 8];
      }
    }
  } else if (bx < 2504) {
    int cid = (bx - 2048) * 256 + tid;
    int pid = cid >> 4;
    int chunk = cid & 15;                    // 16 chunks of 16B per pixel
    int h  = chunk >> 3;                     // ci-half
    int c8 = chunk & 7;
    int b = pid / 228;
    int e = pid - b * 228;
    int ph, pw;
    if (e < 58)       { ph = 0;       pw = e; }
    else if (e < 116) { ph = 57;      pw = e - 58; }
    else if (e < 172) { ph = e - 115; pw = 0; }
    else              { ph = e - 171; pw = 57; }
    f32x4 z = {0.f, 0.f, 0.f, 0.f};
    *(f32x4*)&it[((size_t)(b * 2 + h) * PPIX + ph * PH + pw) * 64 + c8 * 8] = z;
  } else {
    __bf16 (*T)[136] = (__bf16(*)[136])smem;   // [64][136]
    int tx = bx - 2504;
    int b  = tx / 49;
    int p0 = (tx - b * 49) * 64;
    const float* src = in + (size_t)b * CI * NPIX;
#pragma unroll
    for (int jj = 0; jj < 8; ++jj) {
      int c = jj * 256 + tid;
      int ci = c >> 4, xc = c & 15;
      float4 v = *(const float4*)(src + (size_t)ci * NPIX + p0 + xc * 4);
      T[xc * 4 + 0][ci] = (__bf16)v.x;
      T[xc * 4 + 1][ci] = (__bf16)v.y;
      T[xc * 4 + 2][ci] = (__bf16)v.z;
      T[xc * 4 + 3][ci] = (__bf16)v.w;
    }
    __syncthreads();
#pragma unroll
    for (int jj = 0; jj < 4; ++jj) {
      int c = jj * 256 + tid;
      int pl = c >> 4, xc = c & 15;
      int h  = xc >> 3;
      int c8 = xc & 7;
      int pix = p0 + pl;
      int oh = pix / 56, ow = pix - oh * 56;
      int ppix = (oh + 1) * PH + (ow + 1);
      *(f32x4*)&it[((size_t)(b * 2 + h) * PPIX + ppix) * 64 + c8 * 8] =
          *(const f32x4*)&T[pl][xc * 8];
    }
  }
}

// ---------------------------------------------------------------------------
// GEMM/conv with 32x32x16 MFMA (round-8 verified best, final):
//   block = 128 co x 224 n (4 image rows), 4 waves by co-group: wave =
//   32 co x 224 n = 7 n-frags of 32 pixels, acc = 7 x f32x16 (112 AGPR).
//   Per step (one tap x 16 ci): 1 A-load (16B/lane), 7 ds_read_b128,
//   7 v_mfma_f32_32x32x16_bf16.  72 steps = 2 ci-halves x 9 taps x 4 kk.
//   Halo per ci-half: 6 padded rows x 58 px x 144B = 50.1KB LDS; restage at
//   midpoint (2 barriers; otherwise barrier-free).  A: dist-2 register ring.
//   B reads left to the compiler.  setprio retained (R10 A/B: removal -2.5us).
//   A/B frag layout: idx32 = lane&31, k = (lane>>5)*8 + e.  C/D layout
//   (HW-verified m74/m101): col = lane&31, row = (reg&3)+8*(reg>>2)+4*(lane>>5).
//   Grid 14 tiles x 32 b = 448 blocks.
//   Session ledger: 16x16-wide/kg-split/residency/prefetch/B-dbuf variants
//   all regressed or nulled (R1-R7, R9, R10); this structure = best measured.
// ---------------------------------------------------------------------------
__global__ __launch_bounds__(256, 2) void bconv_gemm(
    const __bf16* __restrict__ wt,   // [b][9][128 co][128 ci]
    const __bf16* __restrict__ it,   // [b][2 h][3364 px][64 ci]
    float* __restrict__ out) {       // [b][128 co][3136 n]
  __shared__ __align__(16) char Bsh[HPX4 * SROW2];   // 50112 B
  const int tid  = threadIdx.x;
  const int w    = tid >> 6;
  const int lane = tid & 63;
  const int l31  = lane & 31;
  const int hi8  = lane >> 5;

  // Decode: lin = x + 8*(tile*4 + bhi); b = x + 8*bhi -> same-b blocks share an XCD
  const int lin = blockIdx.x;
  const int x   = lin & 7;
  const int j   = lin >> 3;          // 0..55
  const int bhi = j & 3;
  const int tile = j >> 2;           // 0..13
  const int b   = x + 8 * bhi;
  const int oh0 = tile * 4;          // first output row of this tile

  // ---- halo staging, ci-half 0: 348 px x 8 chunks of 16B = 2784 chunks ----
  const __bf16* hsrc0 = it + ((size_t)(b * 2 + 0) * PPIX + oh0 * PH) * 64;
  const __bf16* hsrc1 = it + ((size_t)(b * 2 + 1) * PPIX + oh0 * PH) * 64;
#pragma unroll
  for (int i = 0; i < 11; ++i) {
    int idx = i * 256 + tid;
    if (idx < HPX4 * 8) {
      int px = idx >> 3, sub = idx & 7;
      *(f32x4*)&Bsh[px * SROW2 + sub * 16] = *(const f32x4*)(hsrc0 + (size_t)idx * 8);
    }
  }
  __syncthreads();

  // ---- per-lane B fragment LDS byte-bases (tap (0,0), kk=0) ----
  // frag nf: pixel n = nf*32 + l31 (flat in the 4x56 tile); k = hi8*8 + e
  int bbase[7];
#pragma unroll
  for (int nf = 0; nf < 7; ++nf) {
    int n = nf * 32 + l31;                   // 0..223
    int orow = n / 56;
    int ocol = n - orow * 56;
    bbase[nf] = (orow * PH + ocol) * SROW2 + hi8 * 16;
  }

  // ---- per-lane A global base (elements): co = co0 + l31, k = hi8*8 + e ----
  const int co0 = w * 32;
  const __bf16* wtb = wt + (size_t)b * 9 * CO * CI;
  const int ab = (co0 + l31) * CI + hi8 * 8;

  f32x16 acc[7] = {};
  // distance-2 A-prefetch ring (statically indexed under full unroll)
  // step t: h = t/36, r = t%36, p = r>>2 (tap), kk = r&3 (16-ci chunk)
  // A element offset = p*CO*CI + h*64 + kk*16
  bf16x8 areg[3];
  areg[0] = *(const bf16x8*)(wtb + ab);          // t=0: p0 kk0 h0
  areg[1] = *(const bf16x8*)(wtb + 16 + ab);     // t=1: p0 kk1 h0

#pragma unroll
  for (int s = 0; s < 72; ++s) {
    if (s == 36) {
      __syncthreads();                       // all waves done reading half 0
#pragma unroll
      for (int i = 0; i < 11; ++i) {
        int idx = i * 256 + tid;
        if (idx < HPX4 * 8) {
          int px = idx >> 3, sub = idx & 7;
          *(f32x4*)&Bsh[px * SROW2 + sub * 16] = *(const f32x4*)(hsrc1 + (size_t)idx * 8);
        }
      }
      __syncthreads();
    }
    // prefetch A for step s+2
    if (s < 70) {
      const int tn  = s + 2;
      const int hn  = tn / 36;
      const int rn  = tn % 36;
      const int pn  = rn >> 2;
      const int kkn = rn & 3;
      areg[tn % 3] = *(const bf16x8*)(wtb + pn * (CO * CI) + hn * 64 + kkn * 16 + ab);
    }
    const int r  = s % 36;
    const int p  = r >> 2;
    const int kk = r & 3;
    const int kh = p / 3, kw = p - kh * 3;
    const int tapb = (kh * PH + kw) * SROW2 + kk * 32;   // compile-time (unrolled)
    __builtin_amdgcn_s_setprio(1);
#pragma unroll
    for (int nf = 0; nf < 7; ++nf) {
      bf16x8 bfr = *(const bf16x8*)&Bsh[bbase[nf] + tapb];
      acc[nf] = __builtin_amdgcn_mfma_f32_32x32x16_bf16(areg[s % 3], bfr, acc[nf], 0, 0, 0);
    }
    __builtin_amdgcn_s_setprio(0);
  }

  // ---- epilogue: col(l31)=n, row = (reg&3)+8*(reg>>2)+4*hi8 = co offset ----
  float* ob = out + (size_t)b * CO * NPIX + oh0 * 56;
#pragma unroll
  for (int nf = 0; nf < 7; ++nf) {
#pragma unroll
    for (int rg = 0; rg < 16; ++rg) {
      int co = co0 + (rg & 3) + 8 * (rg >> 2) + 4 * hi8;
      ob[(size_t)co * NPIX + nf * 32 + l31] = acc[nf][rg];
    }
  }
}

// ---------------------------------------------------------------------------
extern "C" void kernel_launch(void* const* d_in, const int* in_sizes, int n_in,
                              void* d_out, int out_size, void* d_ws, size_t ws_size,
                              hipStream_t stream) {
  const float* inp = (const float*)d_in[0];   // [32,128,56,56]
  const float* eps = (const float*)d_in[1];   // [32,128,128,3,3]
  const float* psi = (const float*)d_in[2];   // [128,128,3,3]
  const float* mu  = (const float*)d_in[3];   // [128,128,3,3]

  // ws layout: wt (9,437,184 B) | it (27,557,888 B)
  __bf16* wt = (__bf16*)d_ws;
  __bf16* it = (__bf16*)((char*)d_ws + 9437184);

  prep_all<<<4072, 256, 0, stream>>>(inp, eps, psi, mu, wt, it);
  bconv_gemm<<<448, 256, 0, stream>>>(wt, it, (float*)d_out);
}